// Round 7
// baseline (101.320 us; speedup 1.0000x reference)
//
#include <hip/hip_runtime.h>
#include <hip/hip_fp16.h>

#define N_HEAD 4
#define F_IN   32
#define F_OUT  32
#define DEG    16

union H4 { ushort4 u; __half h[4]; };
union H8v { uint4 u; __half2 h2[4]; };

__device__ __forceinline__ float4 fma4(float a, float4 x, float4 acc) {
    acc.x = fmaf(a, x.x, acc.x);
    acc.y = fmaf(a, x.y, acc.y);
    acc.z = fmaf(a, x.z, acc.z);
    acc.w = fmaf(a, x.w, acc.w);
    return acc;
}

// Kernel 1 (unchanged): hp[n][h][o] fp16 + a_src/a_dst fp32, XCD-chunked.
__global__ __launch_bounds__(256) void gat_proj(
    const float* __restrict__ h, const float* __restrict__ w,
    const float* __restrict__ fc_w,
    ushort4* __restrict__ hp, float* __restrict__ asrc, float* __restrict__ adst,
    int N)
{
    __shared__ float4 wlds[N_HEAD * F_IN * F_OUT / 4];   // 16 KB
    int t = threadIdx.x;
    const float4* w4g = (const float4*)w;
    wlds[t]       = w4g[t];
    wlds[t + 256] = w4g[t + 256];
    wlds[t + 512] = w4g[t + 512];
    wlds[t + 768] = w4g[t + 768];
    __syncthreads();

    int chunk = gridDim.x >> 3;
    int b  = blockIdx.x;
    int vb = (b & 7) * chunk + (b >> 3);

    int wid  = t >> 6;
    int lane = t & 63;
    int p    = lane >> 5;
    int sub  = lane & 31;
    int hh   = sub >> 3;
    int q    = sub & 7;
    int node0 = vb * 32;
    int base  = node0 + wid * 8 + p * 4;
    bool full = (node0 + 32 <= N);

    float4 acc[4];
    #pragma unroll
    for (int m = 0; m < 4; ++m) acc[m] = make_float4(0.f, 0.f, 0.f, 0.f);

    const float4* h4 = (const float4*)h;
    if (full) {
        #pragma unroll
        for (int c = 0; c < 8; ++c) {
            float4 wv0 = wlds[hh * 256 + (4 * c + 0) * 8 + q];
            float4 wv1 = wlds[hh * 256 + (4 * c + 1) * 8 + q];
            float4 wv2 = wlds[hh * 256 + (4 * c + 2) * 8 + q];
            float4 wv3 = wlds[hh * 256 + (4 * c + 3) * 8 + q];
            #pragma unroll
            for (int m = 0; m < 4; ++m) {
                float4 hv = h4[(base + m) * 8 + c];
                acc[m] = fma4(hv.x, wv0, acc[m]);
                acc[m] = fma4(hv.y, wv1, acc[m]);
                acc[m] = fma4(hv.z, wv2, acc[m]);
                acc[m] = fma4(hv.w, wv3, acc[m]);
            }
        }
    } else {
        #pragma unroll
        for (int c = 0; c < 8; ++c) {
            float4 wv0 = wlds[hh * 256 + (4 * c + 0) * 8 + q];
            float4 wv1 = wlds[hh * 256 + (4 * c + 1) * 8 + q];
            float4 wv2 = wlds[hh * 256 + (4 * c + 2) * 8 + q];
            float4 wv3 = wlds[hh * 256 + (4 * c + 3) * 8 + q];
            #pragma unroll
            for (int m = 0; m < 4; ++m) {
                int node = base + m;
                int nc   = node < N ? node : N - 1;
                float4 hv = h4[nc * 8 + c];
                acc[m] = fma4(hv.x, wv0, acc[m]);
                acc[m] = fma4(hv.y, wv1, acc[m]);
                acc[m] = fma4(hv.z, wv2, acc[m]);
                acc[m] = fma4(hv.w, wv3, acc[m]);
            }
        }
    }

    float4 fs4 = ((const float4*)fc_w)[q];
    float4 fd4 = ((const float4*)fc_w)[8 + q];
    float ps[4], pd[4];
    #pragma unroll
    for (int m = 0; m < 4; ++m) {
        ps[m] = acc[m].x * fs4.x + acc[m].y * fs4.y + acc[m].z * fs4.z + acc[m].w * fs4.w;
        pd[m] = acc[m].x * fd4.x + acc[m].y * fd4.y + acc[m].z * fd4.z + acc[m].w * fd4.w;
    }
    #pragma unroll
    for (int msk = 1; msk <= 4; msk <<= 1) {
        #pragma unroll
        for (int m = 0; m < 4; ++m) {
            ps[m] += __shfl_xor(ps[m], msk, 64);
            pd[m] += __shfl_xor(pd[m], msk, 64);
        }
    }

    #pragma unroll
    for (int m = 0; m < 4; ++m) {
        int node = base + m;
        if (full || node < N) {
            H4 pk;
            pk.h[0] = __float2half_rn(acc[m].x);
            pk.h[1] = __float2half_rn(acc[m].y);
            pk.h[2] = __float2half_rn(acc[m].z);
            pk.h[3] = __float2half_rn(acc[m].w);
            hp[node * 32 + hh * 8 + q] = pk.u;
            if (q == 0) {
                asrc[node * N_HEAD + hh] = ps[m];
                adst[node * N_HEAD + hh] = pd[m];
            }
        }
    }
}

// Kernel 2: 4 nodes/wave, lane = g*16 + r. Packed-half accumulation:
// per edge 4 v_pk_fma_f16 (no cvt) vs previous 8 cvt + 8 fma.
// dst via 1 coalesced dword/lane + LDS; adst via 1 float4 gather/lane + LDS.
__global__ __launch_bounds__(256) void gat_agg(
    const int* __restrict__ dst, const uint4* __restrict__ hp,
    const float* __restrict__ asrc, const float* __restrict__ adst,
    const float* __restrict__ fc_b, const float* __restrict__ bias,
    float* __restrict__ out, int N)
{
    __shared__ int   dk_s[4][64];
    __shared__ float ad_s[4][4 * 68];

    int chunk = gridDim.x >> 3;
    int b  = blockIdx.x;
    int vb = (b & 7) * chunk + (b >> 3);
    int t = threadIdx.x;
    int wid = t >> 6, lane = t & 63;
    int g = lane >> 4, r = lane & 15;
    int wbase = vb * 16 + wid * 4;
    int node  = wbase + g;
    int nodec = node < N ? node : N - 1;
    int c = r >> 2;

    int eidx = wbase * DEG + lane;
    int emax = N * DEG - 1;
    eidx = eidx < emax ? eidx : emax;
    int dval = dst[eidx];
    dk_s[wid][lane] = dval;

    float4 ad4 = ((const float4*)adst)[dval];
    float* ads = &ad_s[wid][g * 68 + r * 4];
    ads[0] = ad4.x; ads[1] = ad4.y; ads[2] = ad4.z; ads[3] = ad4.w;

    __syncthreads();

    float as = asrc[(nodec << 2) + c];
    float bb = fc_b[0];

    // softmax over 16 edges for head c
    float p[16];
    float mx = -1e30f;
    #pragma unroll
    for (int k = 0; k < 16; ++k) {
        float v = as + ad_s[wid][g * 68 + k * 4 + c] + bb;
        v = v > 0.f ? v : 0.2f * v;
        p[k] = v;
        mx = fmaxf(mx, v);
    }
    float s = 0.f;
    #pragma unroll
    for (int k = 0; k < 16; ++k) { p[k] = __expf(p[k] - mx); s += p[k]; }
    float inv = 1.f / s;

    // pre-pack attention weights to half2 (unnormalized)
    __half2 att2[16];
    #pragma unroll
    for (int k = 0; k < 16; ++k) att2[k] = __float2half2_rn(p[k]);

    // packed-half accumulation: 4 pk_fma per edge
    __half2 acc2[4];
    #pragma unroll
    for (int j = 0; j < 4; ++j) acc2[j] = __float2half2_rn(0.f);
    #pragma unroll
    for (int k = 0; k < 16; ++k) {
        int dkk = dk_s[wid][g * 16 + k];
        H8v v; v.u = hp[(dkk << 4) + r];
        #pragma unroll
        for (int j = 0; j < 4; ++j) acc2[j] = __hfma2(att2[k], v.h2[j], acc2[j]);
    }

    // unpack to f32, normalize (per-head inv BEFORE cross-head reduce)
    float acc[8];
    #pragma unroll
    for (int j = 0; j < 4; ++j) {
        float2 f = __half22float2(acc2[j]);
        acc[2 * j]     = f.x * inv;
        acc[2 * j + 1] = f.y * inv;
    }

    // head-mean across c (bits 2,3 of r)
    #pragma unroll
    for (int j = 0; j < 8; ++j) acc[j] += __shfl_xor(acc[j], 4, 64);
    #pragma unroll
    for (int j = 0; j < 8; ++j) acc[j] += __shfl_xor(acc[j], 8, 64);

    if (node < N && r < 4) {
        float4 b0 = ((const float4*)bias)[r * 2];
        float4 b1 = ((const float4*)bias)[r * 2 + 1];
        float4 o0, o1;
        o0.x = 0.25f * acc[0] + b0.x;
        o0.y = 0.25f * acc[1] + b0.y;
        o0.z = 0.25f * acc[2] + b0.z;
        o0.w = 0.25f * acc[3] + b0.w;
        o1.x = 0.25f * acc[4] + b1.x;
        o1.y = 0.25f * acc[5] + b1.y;
        o1.z = 0.25f * acc[6] + b1.z;
        o1.w = 0.25f * acc[7] + b1.w;
        ((float4*)out)[node * 8 + r * 2]     = o0;
        ((float4*)out)[node * 8 + r * 2 + 1] = o1;
    }
}

extern "C" void kernel_launch(void* const* d_in, const int* in_sizes, int n_in,
                              void* d_out, int out_size, void* d_ws, size_t ws_size,
                              hipStream_t stream) {
    const float* h    = (const float*)d_in[0];
    const int*   eidx = (const int*)  d_in[1];
    const float* w    = (const float*)d_in[2];
    const float* fc_w = (const float*)d_in[3];
    const float* fc_b = (const float*)d_in[4];
    const float* bias = (const float*)d_in[5];

    int N = in_sizes[0] / F_IN;
    int E = in_sizes[1] / 2;
    const int* dst = eidx + E;     // edge_index[1]

    ushort4* hp  = (ushort4*)d_ws;                     // N*32 ushort4 (fp16)
    float* asrc  = (float*)(hp + (size_t)N * 32);      // N*4
    float* adst  = asrc + (size_t)N * N_HEAD;          // N*4
    float* out   = (float*)d_out;

    int nbp    = (N + 31) / 32;
    int chunkp = (nbp + 7) / 8;
    gat_proj<<<8 * chunkp, 256, 0, stream>>>(h, w, fc_w, hp, asrc, adst, N);

    int nvb    = (N + 15) / 16;
    int chunka = (nvb + 7) / 8;
    gat_agg<<<8 * chunka, 256, 0, stream>>>(dst, (const uint4*)hp, asrc, adst,
                                            fc_b, bias, out, N);
}